// Round 3
// baseline (531.154 us; speedup 1.0000x reference)
//
#include <hip/hip_runtime.h>
#include <hip/hip_bf16.h>

#define HID 768
#define WROW 1536   // merge_w row stride (floats)
#define NLAB 64

typedef __attribute__((ext_vector_type(8))) __bf16 bf16x8;
typedef __attribute__((ext_vector_type(4))) float f32x4;

__device__ __forceinline__ bf16x8 pk8(float4 a, float4 b) {
    return (bf16x8){(__bf16)a.x, (__bf16)a.y, (__bf16)a.z, (__bf16)a.w,
                    (__bf16)b.x, (__bf16)b.y, (__bf16)b.z, (__bf16)b.w};
}

__device__ __forceinline__ void async16(const void* g, void* l) {
    __builtin_amdgcn_global_load_lds(
        (const __attribute__((address_space(1))) void*)g,
        (__attribute__((address_space(3))) void*)l,
        16, 0, 0);
}

// ---------------------------------------------------------------------------
// Prepass A: fp32 -> bf16, flat grid-stride over 8-element units.
// ---------------------------------------------------------------------------
__global__ __launch_bounds__(256) void cvtA_kernel(
    const float* __restrict__ src, unsigned short* __restrict__ dst, long n8)
{
    long i = (long)blockIdx.x * 256 + threadIdx.x;
    const long stride = (long)gridDim.x * 256;
    for (; i < n8; i += stride) {
        float4 a = *(const float4*)(src + i * 8);
        float4 b = *(const float4*)(src + i * 8 + 4);
        *(bf16x8*)(dst + i * 8) = pk8(a, b);
    }
}

// Prepass W-left: Wb[j][k] = bf16(W[j][k]), k<768.  73728 units, 1 per thread.
__global__ __launch_bounds__(256) void cvtW_kernel(
    const float* __restrict__ W, unsigned short* __restrict__ Wb)
{
    const int u = blockIdx.x * 256 + threadIdx.x;   // 0..73727
    const int j = u / 96;
    const int c = (u % 96) * 8;
    float4 a = *(const float4*)(W + (size_t)j * WROW + c);
    float4 b = *(const float4*)(W + (size_t)j * WROW + c + 4);
    *(bf16x8*)(Wb + (size_t)j * HID + c) = pk8(a, b);
}

// ---------------------------------------------------------------------------
// Kernel 1: P[l][j] = bias[j] + sum_k lf[l][k] * W[j][HID + k]   (all fp32)
// One block per output column j (768 blocks), 256 thr = 64 labels x 4 k-segs.
// ---------------------------------------------------------------------------
__global__ __launch_bounds__(256) void compute_P_kernel(
    const float* __restrict__ lf,    // [64, 768]
    const float* __restrict__ W,     // [768, 1536]
    const float* __restrict__ bias,  // [768]
    float* __restrict__ P)           // [64, 768]
{
    const int j = blockIdx.x;
    const int t = threadIdx.x;
    __shared__ __align__(16) float wrow[HID];
    if (t < 192)
        *(float4*)(wrow + t * 4) =
            *(const float4*)(W + (size_t)j * WROW + HID + t * 4);
    __syncthreads();

    const int lab = t >> 2;          // 0..63
    const int seg = t & 3;           // k-segment of 192
    const float* lfp = lf + lab * HID + seg * 192;
    const float* wp  = wrow + seg * 192;
    float acc = 0.f;
    #pragma unroll 8
    for (int i = 0; i < 192; i += 4) {
        float4 u = *(const float4*)(lfp + i);
        float4 v = *(const float4*)(wp + i);
        acc += u.x * v.x + u.y * v.y + u.z * v.z + u.w * v.w;
    }
    acc += __shfl_xor(acc, 1);       // reduce the 4-lane k-split
    acc += __shfl_xor(acc, 2);
    if (seg == 0) P[lab * HID + j] = acc + bias[j];
}

// ---------------------------------------------------------------------------
// Kernel 2 (new path): bf16 GEMM, m97 structure.
// 128x128 tile, BK=32, 4 waves, global_load_lds(16B) direct to linear bf16
// LDS, double-buffered, ONE barrier per K-step (the __syncthreads drain is
// the known m97-structure stall; accepted).  No staging VGPRs, no in-loop
// cvt -> ~56 VGPR + 64 acc, 4 blocks/CU (LDS-bound at 33 KB).
// ---------------------------------------------------------------------------
__global__ __launch_bounds__(256) void merge_gemm_bf16_kernel(
    const unsigned short* __restrict__ Ab,   // [n, 768] bf16 bits
    const float* __restrict__ A,             // [n, 768] fp32 (passthrough)
    const int* __restrict__ labels,          // [n]
    const unsigned short* __restrict__ Wb,   // [768, 768] bf16 bits
    const float* __restrict__ P,             // [64, 768]
    float* __restrict__ out,                 // [n, 768]
    const int nwg)
{
    __shared__ __align__(16) unsigned short As[2][128 * 32];  // 8 KB each
    __shared__ __align__(16) unsigned short Bs[2][128 * 32];
    __shared__ int Ls[128];

    // bijective XCD-chunk swizzle (nwg = 3072, divisible by 8)
    int bid = blockIdx.x;
    {
        const int q = nwg >> 3;
        bid = (bid & 7) * q + (bid >> 3);
    }
    const int m0 = (bid / (HID / 128)) * 128;
    const int j0 = (bid % (HID / 128)) * 128;

    const int t = threadIdx.x;
    if (t < 128) Ls[t] = labels[m0 + t];

    const int w  = t >> 6;
    const int l  = t & 63;
    const int lm = l & 15;        // row/col inside 16x16 tile
    const int lk = l >> 4;        // k-group 0..3 (8 bf16 each)
    const int qm = (w >> 1) * 64;
    const int qn = (w & 1) * 64;

    // Staging: thread t -> row t>>2 (and +64), 16B chunk t&3.
    // LDS dest element = t*8  (wave-uniform base + lane*16B, required by HW).
    const unsigned short* gA = Ab + (size_t)(m0 + (t >> 2)) * HID + (t & 3) * 8;
    const unsigned short* gB = Wb + (size_t)(j0 + (t >> 2)) * HID + (t & 3) * 8;

    f32x4 acc[4][4] = {};

#define STAGE(buf, K) do { \
    async16(gA + (K),                    &As[buf][t * 8]);        \
    async16(gA + (size_t)64 * HID + (K), &As[buf][t * 8 + 2048]); \
    async16(gB + (K),                    &Bs[buf][t * 8]);        \
    async16(gB + (size_t)64 * HID + (K), &Bs[buf][t * 8 + 2048]); \
} while (0)

#define COMPUTE(buf) do { \
    bf16x8 af[4], bfr[4]; \
    _Pragma("unroll") \
    for (int mi = 0; mi < 4; ++mi) \
        af[mi] = *(const bf16x8*)&As[buf][(qm + mi * 16 + lm) * 32 + lk * 8]; \
    _Pragma("unroll") \
    for (int ni = 0; ni < 4; ++ni) \
        bfr[ni] = *(const bf16x8*)&Bs[buf][(qn + ni * 16 + lm) * 32 + lk * 8]; \
    _Pragma("unroll") \
    for (int mi = 0; mi < 4; ++mi) \
        _Pragma("unroll") \
        for (int ni = 0; ni < 4; ++ni) \
            acc[mi][ni] = __builtin_amdgcn_mfma_f32_16x16x32_bf16( \
                af[mi], bfr[ni], acc[mi][ni], 0, 0, 0); \
} while (0)

    STAGE(0, 0);
    int cur = 0;
    __syncthreads();                       // vmcnt(0) drain + barrier
    for (int k0 = 32; k0 < HID; k0 += 32) {
        STAGE(cur ^ 1, k0);                // next tile in flight
        COMPUTE(cur);
        __syncthreads();                   // drain + barrier; cur^1 now valid,
        cur ^= 1;                          // and all reads of cur are done
    }
    COMPUTE(cur);                          // last tile
#undef STAGE
#undef COMPUTE

    // Epilogue. C/D layout: col = lane&15, row = (lane>>4)*4 + reg  [m89/m91]
    #pragma unroll
    for (int mi = 0; mi < 4; ++mi) {
        const int rowb = qm + mi * 16 + lk * 4;
        #pragma unroll
        for (int r = 0; r < 4; ++r) {
            const int n_tok = m0 + rowb + r;
            const int lab   = Ls[rowb + r];
            const size_t rowoff = (size_t)n_tok * HID;
            #pragma unroll
            for (int ni = 0; ni < 4; ++ni) {
                const int j = j0 + qn + ni * 16 + lm;
                float v;
                if (lab != 0)
                    v = acc[mi][ni][r] + P[(size_t)(lab - 1) * HID + j];
                else
                    v = A[rowoff + j];
                out[rowoff + j] = v;
            }
        }
    }
}

// ---------------------------------------------------------------------------
// Kernel 2 (fallback path, ws too small): Round-2 reg-staged kernel.
// ---------------------------------------------------------------------------
__global__ __launch_bounds__(256) void merge_gemm_kernel(
    const float* __restrict__ A,
    const int* __restrict__ labels,
    const float* __restrict__ W,
    const float* __restrict__ P,
    float* __restrict__ out,
    const int nwg)
{
    __shared__ __align__(16) unsigned short As[2][128 * 32];
    __shared__ __align__(16) unsigned short Bs[2][128 * 32];
    __shared__ int Ls[128];

    int bid = blockIdx.x;
    if ((nwg & 7) == 0) {
        const int q = nwg >> 3;
        bid = (bid & 7) * q + (bid >> 3);
    }
    const int m0 = (bid / (HID / 128)) * 128;
    const int j0 = (bid % (HID / 128)) * 128;

    const int t = threadIdx.x;
    if (t < 128) Ls[t] = labels[m0 + t];

    const int w  = t >> 6;
    const int l  = t & 63;
    const int lm = l & 15;
    const int lk = l >> 4;
    const int qm = (w >> 1) * 64;
    const int qn = (w & 1) * 64;

    const int sr = t >> 2;
    const int sc = t & 3;
    const float* gA  = A + (size_t)(m0 + sr) * HID  + sc * 8;
    const float* gA2 = gA + (size_t)64 * HID;
    const float* gB  = W + (size_t)(j0 + sr) * WROW + sc * 8;
    const float* gB2 = gB + (size_t)64 * WROW;
    const int eoff = sr * 32 + ((sc ^ (sr & 3)) * 8);

    float4 ra0, ra1, ra2, ra3, rb0, rb1, rb2, rb3;
    f32x4 acc[4][4] = {};

#define ISSUE(K) do { \
    ra0 = *(const float4*)(gA  + (K));      ra1 = *(const float4*)(gA  + (K) + 4); \
    ra2 = *(const float4*)(gA2 + (K));      ra3 = *(const float4*)(gA2 + (K) + 4); \
    rb0 = *(const float4*)(gB  + (K));      rb1 = *(const float4*)(gB  + (K) + 4); \
    rb2 = *(const float4*)(gB2 + (K));      rb3 = *(const float4*)(gB2 + (K) + 4); \
} while (0)

    ISSUE(0);
    int p = 0;
    for (int k0 = 0; k0 < HID; k0 += 32) {
        *(bf16x8*)&As[p][eoff]        = pk8(ra0, ra1);
        *(bf16x8*)&As[p][eoff + 2048] = pk8(ra2, ra3);
        *(bf16x8*)&Bs[p][eoff]        = pk8(rb0, rb1);
        *(bf16x8*)&Bs[p][eoff + 2048] = pk8(rb2, rb3);
        if (k0 + 32 < HID) ISSUE(k0 + 32);
        __syncthreads();

        bf16x8 af[4], bfr[4];
        #pragma unroll
        for (int mi = 0; mi < 4; ++mi) {
            const int r = qm + mi * 16 + lm;
            af[mi] = *(const bf16x8*)&As[p][r * 32 + ((lk ^ (r & 3)) * 8)];
        }
        #pragma unroll
        for (int ni = 0; ni < 4; ++ni) {
            const int r = qn + ni * 16 + lm;
            bfr[ni] = *(const bf16x8*)&Bs[p][r * 32 + ((lk ^ (r & 3)) * 8)];
        }
        #pragma unroll
        for (int mi = 0; mi < 4; ++mi)
            #pragma unroll
            for (int ni = 0; ni < 4; ++ni)
                acc[mi][ni] = __builtin_amdgcn_mfma_f32_16x16x32_bf16(
                    af[mi], bfr[ni], acc[mi][ni], 0, 0, 0);
        p ^= 1;
    }
#undef ISSUE

    #pragma unroll
    for (int mi = 0; mi < 4; ++mi) {
        const int rowb = qm + mi * 16 + lk * 4;
        #pragma unroll
        for (int r = 0; r < 4; ++r) {
            const int n_tok = m0 + rowb + r;
            const int lab   = Ls[rowb + r];
            const size_t rowoff = (size_t)n_tok * HID;
            #pragma unroll
            for (int ni = 0; ni < 4; ++ni) {
                const int j = j0 + qn + ni * 16 + lm;
                float v;
                if (lab != 0)
                    v = acc[mi][ni][r] + P[(size_t)(lab - 1) * HID + j];
                else
                    v = A[rowoff + j];
                out[rowoff + j] = v;
            }
        }
    }
}

extern "C" void kernel_launch(void* const* d_in, const int* in_sizes, int n_in,
                              void* d_out, int out_size, void* d_ws, size_t ws_size,
                              hipStream_t stream) {
    const float* com    = (const float*)d_in[0];  // [16,4096,768] fp32
    const int*   labels = (const int*)d_in[1];    // [16,4096] int32
    const float* lf     = (const float*)d_in[2];  // [64,768] fp32
    const float* W      = (const float*)d_in[3];  // [768,1536] fp32
    const float* bias   = (const float*)d_in[4];  // [768] fp32
    float* out = (float*)d_out;

    const int n_rows = in_sizes[0] / HID;         // 65536
    const int nwg = (n_rows / 128) * (HID / 128); // 3072

    // ws layout: P fp32 [64*768] | Wb bf16 [768*768] | Ab bf16 [n_rows*768]
    float* P = (float*)d_ws;
    const size_t off_Wb = (size_t)NLAB * HID * 4;              // 196608
    const size_t off_Ab = off_Wb + (size_t)HID * HID * 2;      // 1376256
    const size_t need   = off_Ab + (size_t)n_rows * HID * 2;   // ~102 MB

    if (ws_size >= need) {
        unsigned short* Wb = (unsigned short*)((char*)d_ws + off_Wb);
        unsigned short* Ab = (unsigned short*)((char*)d_ws + off_Ab);
        const long n8 = (long)n_rows * HID / 8;
        cvtA_kernel<<<dim3(2048), dim3(256), 0, stream>>>(com, Ab, n8);
        cvtW_kernel<<<dim3(HID * 96 / 256), dim3(256), 0, stream>>>(W, Wb);
        compute_P_kernel<<<dim3(HID), dim3(256), 0, stream>>>(lf, W, bias, P);
        merge_gemm_bf16_kernel<<<dim3(nwg), dim3(256), 0, stream>>>(
            Ab, com, labels, Wb, P, out, nwg);
    } else {
        compute_P_kernel<<<dim3(HID), dim3(256), 0, stream>>>(lf, W, bias, P);
        merge_gemm_kernel<<<dim3(nwg), dim3(256), 0, stream>>>(
            com, labels, W, P, out, nwg);
    }
}